// Round 1
// baseline (117.641 us; speedup 1.0000x reference)
//
#include <hip/hip_runtime.h>

// Closed form of the reference (exact, since SIG = 1/sqrt(2pi) makes log_sqrt_pi = 0):
//   out = D + 0.5 * sum_{k=0}^{D-1} [ e^{-pi*(y[k+1]-y[k])^2} + e^{-pi*(d[k+1]-d[k])^2}
//                                   - e^{-pi*(d[k+1]-y[k+1])^2} - e^{-pi*(d[k+1]-y[k])^2}
//                                   - e^{-pi*(d[k]-y[k+1])^2}   - e^{-pi*(d[k]-y[k])^2} ]
// with D = N-2.
//
// R2 lesson: same-address atomicAdds serialize at the coherence point.
// R3 (this version): fuse the two kernels. Per-block partials to ws (release
// store, agent scope), atomic counter; the LAST block to finish reduces the
// 1024 partials and writes out[0]. Counter is zeroed by a 4-byte memset node
// (graph-capturable), since ws is poisoned by the harness. No spin-wait, so
// no co-residency requirement.

#define PI_F 3.14159265358979323846f
#define NBLOCKS 1024
#define NTHREADS 256

__device__ __forceinline__ float six_terms(float d0, float d1, float y0, float y1) {
    float dy = y1 - y0;
    float dd = d1 - d0;
    float c00 = d1 - y1;
    float c01 = d1 - y0;
    float c10 = d0 - y1;
    float c11 = d0 - y0;
    return __expf(-PI_F * dy * dy) + __expf(-PI_F * dd * dd)
         - __expf(-PI_F * c00 * c00) - __expf(-PI_F * c01 * c01)
         - __expf(-PI_F * c10 * c10) - __expf(-PI_F * c11 * c11);
}

__global__ __launch_bounds__(NTHREADS) void casamento_fused(
    const float* __restrict__ d, const float* __restrict__ y,
    float* __restrict__ ws, unsigned* __restrict__ ctr,
    float* __restrict__ out, int D)
{
    int tid = blockIdx.x * blockDim.x + threadIdx.x;
    int stride = gridDim.x * blockDim.x;
    int D4 = D >> 2;

    float acc = 0.0f;
    for (int u = tid; u < D4; u += stride) {
        int base = u << 2;
        float4 dv = *(const float4*)(d + base);
        float4 yv = *(const float4*)(y + base);
        float d4 = d[base + 4];   // L1 hit: neighbor's cacheline
        float y4 = y[base + 4];

        acc += six_terms(dv.x, dv.y, yv.x, yv.y);
        acc += six_terms(dv.y, dv.z, yv.y, yv.z);
        acc += six_terms(dv.z, dv.w, yv.z, yv.w);
        acc += six_terms(dv.w, d4,   yv.w, y4);
    }

    // tail (D % 4 != 0): thread 0 mops up (<=3 elements; empty for N=4000002)
    if (tid == 0) {
        for (int k = (D4 << 2); k < D; ++k)
            acc += six_terms(d[k], d[k + 1], y[k], y[k + 1]);
    }

    acc *= 0.5f;

    // wave-64 butterfly reduce
    for (int off = 32; off > 0; off >>= 1)
        acc += __shfl_down(acc, off, 64);

    __shared__ float warp_sums[NTHREADS / 64];
    __shared__ bool  is_last;
    int lane = threadIdx.x & 63;
    int wid  = threadIdx.x >> 6;
    if (lane == 0) warp_sums[wid] = acc;
    __syncthreads();

    if (threadIdx.x == 0) {
        float bsum = warp_sums[0] + warp_sums[1] + warp_sums[2] + warp_sums[3];
        // release store so the last block's acquire sees it (agent scope -> L2-coherent)
        __hip_atomic_store(&ws[blockIdx.x], bsum, __ATOMIC_RELEASE,
                           __HIP_MEMORY_SCOPE_AGENT);
        unsigned old = __hip_atomic_fetch_add(ctr, 1u, __ATOMIC_ACQ_REL,
                                              __HIP_MEMORY_SCOPE_AGENT);
        is_last = (old == (unsigned)(gridDim.x - 1));
    }
    __syncthreads();

    if (is_last) {  // uniform per-block branch
        float s = 0.0f;
        for (int i = threadIdx.x; i < NBLOCKS; i += NTHREADS)
            s += __hip_atomic_load(&ws[i], __ATOMIC_RELAXED,
                                   __HIP_MEMORY_SCOPE_AGENT);
        for (int off = 32; off > 0; off >>= 1)
            s += __shfl_down(s, off, 64);
        if (lane == 0) warp_sums[wid] = s;
        __syncthreads();
        if (threadIdx.x == 0)
            out[0] = warp_sums[0] + warp_sums[1] + warp_sums[2] + warp_sums[3]
                   + (float)D;   // plain store — overwrites the 0xAA poison
    }
}

extern "C" void kernel_launch(void* const* d_in, const int* in_sizes, int n_in,
                              void* d_out, int out_size, void* d_ws, size_t ws_size,
                              hipStream_t stream) {
    const float* d = (const float*)d_in[0];
    const float* y = (const float*)d_in[1];
    float* out = (float*)d_out;
    float* ws  = (float*)d_ws;                    // NBLOCKS floats of scratch
    unsigned* ctr = (unsigned*)(ws + NBLOCKS);    // 4-byte counter after partials

    int N = in_sizes[0];
    int D = N - 2;

    hipMemsetAsync(ctr, 0, sizeof(unsigned), stream);  // graph-capturable memset node
    casamento_fused<<<NBLOCKS, NTHREADS, 0, stream>>>(d, y, ws, ctr, out, D);
}

// Round 2
// 75.868 us; speedup vs baseline: 1.5506x; 1.5506x over previous
//
#include <hip/hip_runtime.h>

// Closed form of the reference (exact, since SIG = 1/sqrt(2pi) makes log_sqrt_pi = 0):
//   out = D + 0.5 * sum_{k=0}^{D-1} [ e^{-pi*(y[k+1]-y[k])^2} + e^{-pi*(d[k+1]-d[k])^2}
//                                   - e^{-pi*(d[k+1]-y[k+1])^2} - e^{-pi*(d[k+1]-y[k])^2}
//                                   - e^{-pi*(d[k]-y[k+1])^2}   - e^{-pi*(d[k]-y[k])^2} ]
// with D = N-2.
//
// R2 lesson: same-address atomicAdds serialize at the coherence point (~14 ns each).
// R3 lesson: fusing stage 2 via an atomic block-counter re-created exactly that
//   serialization (1024 near-simultaneous fetch_adds, kernel 25->53 us). Reverted.
// R4 (this version): two kernels again, but stage 1 is ONE-SHOT (no grid-stride
//   loop). Each thread owns 8 consecutive elements: 2xfloat4 + 1 scalar per input,
//   all loads issued before a single waitcnt (max MLP, no per-iteration latency
//   exposure). Grid ~1954 blocks -> ~7.6 blocks/CU -> ~95% occupancy (vs 50% cap
//   at 1024 blocks).

#define PI_F 3.14159265358979323846f
#define NTHREADS 256
#define ELEMS_PER_THREAD 8
#define FINAL_THREADS 1024

__device__ __forceinline__ float six_terms(float d0, float d1, float y0, float y1) {
    float dy = y1 - y0;
    float dd = d1 - d0;
    float c00 = d1 - y1;
    float c01 = d1 - y0;
    float c10 = d0 - y1;
    float c11 = d0 - y0;
    return __expf(-PI_F * dy * dy) + __expf(-PI_F * dd * dd)
         - __expf(-PI_F * c00 * c00) - __expf(-PI_F * c01 * c01)
         - __expf(-PI_F * c10 * c10) - __expf(-PI_F * c11 * c11);
}

// Stage 1: one-shot, 8 elements/thread, per-block partial sum to ws[blockIdx].
__global__ __launch_bounds__(NTHREADS) void casamento_partial(
    const float* __restrict__ d, const float* __restrict__ y,
    float* __restrict__ ws, int D)
{
    int gtid = blockIdx.x * NTHREADS + threadIdx.x;
    int base = gtid * ELEMS_PER_THREAD;

    float acc = 0.0f;
    if (base + ELEMS_PER_THREAD <= D) {
        // 6 loads issued back-to-back; single waitcnt before compute.
        float4 a = *(const float4*)(d + base);
        float4 b = *(const float4*)(d + base + 4);
        float4 p = *(const float4*)(y + base);
        float4 q = *(const float4*)(y + base + 4);
        float d8 = d[base + 8];   // base+8 <= D = N-2 < N, in bounds
        float y8 = y[base + 8];

        acc += six_terms(a.x, a.y, p.x, p.y);
        acc += six_terms(a.y, a.z, p.y, p.z);
        acc += six_terms(a.z, a.w, p.z, p.w);
        acc += six_terms(a.w, b.x, p.w, q.x);
        acc += six_terms(b.x, b.y, q.x, q.y);
        acc += six_terms(b.y, b.z, q.y, q.z);
        acc += six_terms(b.z, b.w, q.z, q.w);
        acc += six_terms(b.w, d8,  q.w, y8);
    } else if (base < D) {
        // ragged tail (empty for N=4000002 since D % 8 == 0)
        for (int k = base; k < D; ++k)
            acc += six_terms(d[k], d[k + 1], y[k], y[k + 1]);
    }

    acc *= 0.5f;

    // wave-64 butterfly reduce
    for (int off = 32; off > 0; off >>= 1)
        acc += __shfl_down(acc, off, 64);

    __shared__ float warp_sums[NTHREADS / 64];
    int lane = threadIdx.x & 63;
    int wid  = threadIdx.x >> 6;
    if (lane == 0) warp_sums[wid] = acc;
    __syncthreads();

    if (threadIdx.x == 0)
        ws[blockIdx.x] = warp_sums[0] + warp_sums[1] + warp_sums[2] + warp_sums[3];
}

// Stage 2: one block reduces NB partials, adds constant D, writes out[0].
__global__ __launch_bounds__(FINAL_THREADS) void casamento_final(
    const float* __restrict__ ws, float* __restrict__ out, int D, int NB)
{
    float acc = 0.0f;
    for (int i = threadIdx.x; i < NB; i += FINAL_THREADS)
        acc += ws[i];

    for (int off = 32; off > 0; off >>= 1)
        acc += __shfl_down(acc, off, 64);

    __shared__ float warp_sums[FINAL_THREADS / 64];
    int lane = threadIdx.x & 63;
    int wid  = threadIdx.x >> 6;
    if (lane == 0) warp_sums[wid] = acc;
    __syncthreads();

    if (threadIdx.x == 0) {
        float s = 0.0f;
        #pragma unroll
        for (int i = 0; i < FINAL_THREADS / 64; ++i) s += warp_sums[i];
        out[0] = s + (float)D;   // plain store — overwrites the 0xAA poison
    }
}

extern "C" void kernel_launch(void* const* d_in, const int* in_sizes, int n_in,
                              void* d_out, int out_size, void* d_ws, size_t ws_size,
                              hipStream_t stream) {
    const float* d = (const float*)d_in[0];
    const float* y = (const float*)d_in[1];
    float* out = (float*)d_out;
    float* ws  = (float*)d_ws;

    int N = in_sizes[0];
    int D = N - 2;

    int units = (D + ELEMS_PER_THREAD - 1) / ELEMS_PER_THREAD;   // threads needed
    int NB = (units + NTHREADS - 1) / NTHREADS;                  // 1954 for N=4000002

    casamento_partial<<<NB, NTHREADS, 0, stream>>>(d, y, ws, D);
    casamento_final<<<1, FINAL_THREADS, 0, stream>>>(ws, out, D, NB);
}